// Round 11
// baseline (141.717 us; speedup 1.0000x reference)
//
#include <hip/hip_runtime.h>
#include <hip/hip_bf16.h>

#define B_ 8
#define D_ 128
#define S_ 4096

typedef short short8 __attribute__((ext_vector_type(8)));
typedef float f32x4  __attribute__((ext_vector_type(4)));
typedef float f32x16 __attribute__((ext_vector_type(16)));
typedef unsigned int uint;
typedef uint uint4v __attribute__((ext_vector_type(4)));

#define EXP2F(x) exp2f(x)

__device__ __forceinline__ short f2bf(float f) {
    __hip_bfloat16 h = __float2bfloat16(f);
    return *reinterpret_cast<short*>(&h);
}

// pack two f32 -> one u32 of 2 bf16 (elem0 = lo word)
__device__ __forceinline__ uint cvtpk(float lo, float hi) {
    uint r;
    asm("v_cvt_pk_bf16_f32 %0, %1, %2" : "=v"(r) : "v"(lo), "v"(hi));
    return r;
}

// async global->LDS DMA, 16B/lane; LDS dest = wave-uniform base + lane*16
__device__ __forceinline__ void gload16(const void* g, void* l) {
    __builtin_amdgcn_global_load_lds(
        (const __attribute__((address_space(1))) void*)g,
        (__attribute__((address_space(3))) void*)l, 16, 0, 0);
}

__device__ __forceinline__ float max3f(float a, float b, float c) {
    return fmaxf(fmaxf(a, b), c);    // clang fuses to v_max3_f32
}

// ---------------------------------------------------------------------------
// Kernel 0: pack Wq/Wk/Wv into bf16 MFMA fragments (16x16x32 layout for qkv).
// ---------------------------------------------------------------------------
__global__ __launch_bounds__(256) void wpack_kernel(
    const float* __restrict__ Wq, const float* __restrict__ Wk,
    const float* __restrict__ Wv, short* __restrict__ Wf)
{
    int g = blockIdx.x * 256 + threadIdx.x;      // 0..6143
    int lane = g & 63, kc = (g >> 6) & 3, n = (g >> 8) & 7, wm = g >> 11;
    const float* W = (wm == 0) ? Wq : (wm == 1) ? Wk : Wv;
    int row = n * 16 + (lane & 15);
    int col = kc * 32 + (lane >> 4) * 8;
    short8 o;
    #pragma unroll
    for (int j = 0; j < 8; ++j) o[j] = f2bf(W[row * 128 + col + j]);
    *((short8*)Wf + g) = o;
}

// ---------------------------------------------------------------------------
// Kernel 1: QKV projection via bf16 MFMA (16x16x32), unchanged.
// Q: (B,S,D) bf16 scaled by log2(e)/sqrt(D). K: (B,S,D). V: (B,D,S).
// ---------------------------------------------------------------------------
__global__ __launch_bounds__(256) void qkv_kernel(
    const float* __restrict__ x, const short* __restrict__ Wf,
    const float* __restrict__ bq, const float* __restrict__ bk,
    const float* __restrict__ bv,
    short* __restrict__ Qo, short* __restrict__ Ko, short* __restrict__ Vo)
{
    __shared__ float xt[64 * 132];
    const int b  = blockIdx.y;
    const int s0 = blockIdx.x * 64;
    const int t  = threadIdx.x;
    const int w    = t >> 6;
    const int lane = t & 63;
    const int lr   = lane & 15;
    const int lg   = lane >> 4;

    const float* xb = x + (size_t)b * D_ * S_;
    #pragma unroll
    for (int it = 0; it < 32; ++it) {
        int d = it * 4 + (t >> 6);
        int s = t & 63;
        xt[s * 132 + d] = xb[(size_t)d * S_ + s0 + s];
    }
    __syncthreads();

    short8 xtf[4];
    {
        const float* base = &xt[(w * 16 + lr) * 132 + lg * 8];
        #pragma unroll
        for (int kc = 0; kc < 4; ++kc) {
            float4 a = *(const float4*)(base + kc * 32);
            float4 c = *(const float4*)(base + kc * 32 + 4);
            short8 f;
            f[0] = f2bf(a.x); f[1] = f2bf(a.y); f[2] = f2bf(a.z); f[3] = f2bf(a.w);
            f[4] = f2bf(c.x); f[5] = f2bf(c.y); f[6] = f2bf(c.z); f[7] = f2bf(c.w);
            xtf[kc] = f;
        }
    }

    const float qs = 0.08838834764831845f * 1.4426950408889634f;
    const short8* W8 = (const short8*)Wf;
    const size_t bSD = (size_t)b * S_ * D_;
    const size_t bDS = (size_t)b * D_ * S_;

    #pragma unroll
    for (int n = 0; n < 8; ++n) {
        f32x4 aq = (f32x4){0.f, 0.f, 0.f, 0.f};
        f32x4 ak = (f32x4){0.f, 0.f, 0.f, 0.f};
        f32x4 av = (f32x4){0.f, 0.f, 0.f, 0.f};
        #pragma unroll
        for (int kc = 0; kc < 4; ++kc) {
            short8 wq = W8[(      n * 4 + kc) * 64 + lane];
            short8 wk = W8[(32  + n * 4 + kc) * 64 + lane];
            short8 wv = W8[(64  + n * 4 + kc) * 64 + lane];
            aq = __builtin_amdgcn_mfma_f32_16x16x32_bf16(xtf[kc], wq, aq, 0, 0, 0);
            ak = __builtin_amdgcn_mfma_f32_16x16x32_bf16(xtf[kc], wk, ak, 0, 0, 0);
            av = __builtin_amdgcn_mfma_f32_16x16x32_bf16(wv, xtf[kc], av, 0, 0, 0);
        }
        int e = n * 16 + lr;
        float bqe = bq[e], bke = bk[e];
        #pragma unroll
        for (int r = 0; r < 4; ++r) {
            size_t off = (bSD + (size_t)(s0 + w * 16 + lg * 4 + r) * D_) + e;
            Qo[off] = f2bf((aq[r] + bqe) * qs);
            Ko[off] = f2bf(ak[r] + bke);
        }
        #pragma unroll
        for (int r = 0; r < 4; ++r) {
            int ev = n * 16 + lg * 4 + r;
            Vo[bDS + (size_t)ev * S_ + s0 + w * 16 + lr] = f2bf(av[r] + bv[ev]);
        }
    }
}

// ---------------------------------------------------------------------------
// Kernel 2: flash attention (R9 base: 512 thr, 2 KV-halves x 4 q-strips,
// 64-kv tiles, K+V DMA-staged, dbuf, 1 barrier/tile; depth-2-pair LDS read
// prefetch; lane-partial lsum; v_max3 tree) + ADDRESS-MATH REDUCTION:
// the swizzled read offset ((X^(q&7))*16, X=c*2+hi or kc*2+hi) is
// XOR-separable into bit-disjoint fields:
//   addr = (base + q*row + ((q&7)^hi)*16) ^ (c*32)   [+ row-imm offset]
// so the per-lane base is hoisted once per buffer and EVERY fragment read is
// one v_xor with an inline constant (compiler folds row/dt into ds_read
// offset:N). Also: persistent zero16 as C-operand of the first QK MFMA pair
// kills the 32 per-tile acc-init v_movs. (R10 post-mortem: VALUBusy likely
// includes MFMA via gfx94x fallback formula; true VALU had ~250 cyc/wave/tile
// of addressing+init overhead -- this round removes it.)
// C/D layout (m74/m101): col=lane&31, row=(reg&3)+8*(reg>>2)+4*(lane>>5).
// ---------------------------------------------------------------------------
__global__ __launch_bounds__(512, 2) void attn_kernel(
    const short* __restrict__ Q, const short* __restrict__ K,
    const short* __restrict__ Vt, const float* __restrict__ x,
    float* __restrict__ out)
{
    extern __shared__ __align__(16) char smem[];   // 131072 B
    const int lin = blockIdx.x;
    const int b   = lin & 7;            // XCD swizzle: one b per XCD
    const int q0  = (lin >> 3) * 128;
    const int tid  = threadIdx.x;
    const int w    = tid >> 6;
    const int lane = tid & 63;
    const int q    = lane & 31;         // this lane's q column
    const int hi   = lane >> 5;
    const int half = w >> 2;            // KV half: kt 0..31 -> rows half*2048..
    const int ww   = w & 3;             // q strip (q0 + ww*32 ..)
    const uint kx  = (uint)(((q & 7) ^ hi) * 16);   // hoisted swizzle base

    const size_t bSD = (size_t)b * S_ * D_;

    // Q fragments: qf[c][j] = Q[q0+ww*32+q][c*16 + hi*8 + j]
    short8 qf[8];
    {
        const short* Qrow = Q + bSD + (size_t)(q0 + ww * 32 + q) * D_ + hi * 8;
        #pragma unroll
        for (int c = 0; c < 8; ++c)
            qf[c] = *(const short8*)(Qrow + c * 16);
    }

    f32x16 o[4];
    #pragma unroll
    for (int dt = 0; dt < 4; ++dt)
        #pragma unroll
        for (int i = 0; i < 16; ++i) o[dt][i] = 0.f;
    float m = -1e30f, lsum = 0.f;      // lsum LANE-PARTIAL until after loop

    // Persistent zero accumulator: C-operand of the first QK MFMA pair;
    // zeroed ONCE here instead of 32 v_movs per tile.
    f32x16 zero16;
    #pragma unroll
    for (int i = 0; i < 16; ++i) zero16[i] = 0.f;

    const short* Kb = K + bSD;
    const short* Vb = Vt + (size_t)b * D_ * S_;
    const int ktbase = half * 32;

    // DMA-stage one 64-kv tile of this wave's half into buffer `buf`.
    // LDS dest linear; global src pre-swizzled (phys 16B-chunk c of row r
    // holds logical chunk c^(r&7)).
    auto stage = [&](int kt, int buf) {
        const short* Kg = Kb + (size_t)(ktbase + kt) * 64 * D_;
        const short* Vg = Vb + (size_t)(ktbase + kt) * 64;
        char* Kd = smem + buf * 65536 + half * 32768;
        char* Vd = Kd + 16384;
        #pragma unroll
        for (int i = 0; i < 4; ++i) {
            int ki = ww * 4 + i;                 // 1KB chunk: rows 4ki..4ki+3
            int r  = ki * 4 + (lane >> 4);
            gload16(Kg + r * D_ + (((lane & 15) ^ (r & 7)) * 8), Kd + ki * 1024);
        }
        #pragma unroll
        for (int i = 0; i < 4; ++i) {
            int vi = ww * 4 + i;                 // 1KB chunk: rows 8vi..8vi+7
            int r  = vi * 8 + (lane >> 3);
            gload16(Vg + (size_t)r * S_ + (((lane & 7) ^ (lane >> 3)) * 8),
                    Vd + vi * 1024);
        }
    };

    stage(0, 0);
    __syncthreads();                 // drains vmcnt -> buf0 ready
    int cur = 0;

    for (int kt = 0; kt < 32; ++kt) {
        if (kt + 1 < 32) stage(kt + 1, cur ^ 1);   // DMA overlaps compute

        const char* Kh = smem + cur * 65536 + half * 32768;
        // Hoisted per-lane XOR-separable bases (one v_xor per fragment read):
        //   K read c, row n: *(Kq ^ (c*32) + n*8192)
        //   V read kc, dt:   *(Vq ^ (kc*32) + dt*4096)
        const uintptr_t Kq = (uintptr_t)Kh + (uint)(q * 256) + kx;
        const uintptr_t Vq = (uintptr_t)(Kh + 16384) + (uint)(q * 128) + kx;

        // ---- S^T = K Q^T : acc[n][r] = S[k = n*32+(r&3)+8*(r>>2)+4*hi][q] --
        // Depth-2-pair rotating prefetch (reads for c+2 issued at step c).
        f32x16 acc0, acc1;
        short8 kf[3][2];
        kf[0][0] = *(const short8*)(Kq);
        kf[0][1] = *(const short8*)(Kq + 8192);
        kf[1][0] = *(const short8*)(Kq ^ 32u);
        kf[1][1] = *(const short8*)((Kq ^ 32u) + 8192);
        __builtin_amdgcn_s_setprio(1);
        #pragma unroll
        for (int c = 0; c < 8; ++c) {
            if (c < 6) {
                uintptr_t a = Kq ^ (uint)((c + 2) * 32);
                kf[(c + 2) % 3][0] = *(const short8*)(a);
                kf[(c + 2) % 3][1] = *(const short8*)(a + 8192);
            }
            if (c == 0) {
                acc0 = __builtin_amdgcn_mfma_f32_32x32x16_bf16(kf[0][0], qf[0], zero16, 0, 0, 0);
                acc1 = __builtin_amdgcn_mfma_f32_32x32x16_bf16(kf[0][1], qf[0], zero16, 0, 0, 0);
            } else {
                acc0 = __builtin_amdgcn_mfma_f32_32x32x16_bf16(kf[c % 3][0], qf[c], acc0, 0, 0, 0);
                acc1 = __builtin_amdgcn_mfma_f32_32x32x16_bf16(kf[c % 3][1], qf[c], acc1, 0, 0, 0);
            }
        }
        __builtin_amdgcn_s_setprio(0);

        // ---- tile max: 3-ary tree (v_max3), then cross-half, T13 gate ----
        float a0 = max3f(acc0[0],  acc0[1],  acc0[2]);
        float a1 = max3f(acc0[3],  acc0[4],  acc0[5]);
        float a2 = max3f(acc0[6],  acc0[7],  acc0[8]);
        float a3 = max3f(acc0[9],  acc0[10], acc0[11]);
        float a4 = max3f(acc0[12], acc0[13], acc0[14]);
        float a5 = max3f(acc1[0],  acc1[1],  acc1[2]);
        float a6 = max3f(acc1[3],  acc1[4],  acc1[5]);
        float a7 = max3f(acc1[6],  acc1[7],  acc1[8]);
        float a8 = max3f(acc1[9],  acc1[10], acc1[11]);
        float a9 = max3f(acc1[12], acc1[13], acc1[14]);
        float b0 = max3f(a0, a1, a2);
        float b1 = max3f(a3, a4, acc0[15]);
        float b2 = max3f(a5, a6, a7);
        float b3 = max3f(a8, a9, acc1[15]);
        float tm = fmaxf(max3f(b0, b1, b2), b3);
        tm = fmaxf(tm, __shfl_xor(tm, 32));
        if (!__all(tm <= m + 8.f)) {
            float mn   = fmaxf(m, tm);
            float corr = EXP2F(m - mn);
            m = mn; lsum *= corr;
            #pragma unroll
            for (int dt = 0; dt < 4; ++dt)
                #pragma unroll
                for (int r = 0; r < 16; ++r) o[dt][r] *= corr;
        }
        #pragma unroll
        for (int r = 0; r < 16; ++r) acc0[r] = EXP2F(acc0[r] - m);
        #pragma unroll
        for (int r = 0; r < 16; ++r) acc1[r] = EXP2F(acc1[r] - m);

        // ---- P -> bf16 PV B-fragments (distinct SSA defs -> permlane safe) --
        short8 pf[4];
        #pragma unroll
        for (int kc = 0; kc < 4; ++kc) {
            const f32x16& a = (kc < 2) ? acc0 : acc1;
            int c1 = (kc & 1) * 8;
            uint W0 = cvtpk(a[c1 + 0], a[c1 + 1]);
            uint W1 = cvtpk(a[c1 + 2], a[c1 + 3]);
            uint W2 = cvtpk(a[c1 + 4], a[c1 + 5]);
            uint W3 = cvtpk(a[c1 + 6], a[c1 + 7]);
            asm("v_permlane32_swap_b32 %0, %1" : "+v"(W0), "+v"(W2));
            asm("v_permlane32_swap_b32 %0, %1" : "+v"(W1), "+v"(W3));
            uint4v pw;
            pw.x = W0; pw.y = W1; pw.z = W2; pw.w = W3;
            pf[kc] = *reinterpret_cast<short8*>(&pw);
        }

        // ---- V prefetch (2 pairs), then sums (hide under PV), then PV ----
        short8 vf[3][2];
        vf[0][0] = *(const short8*)(Vq);            // i=0: kc=0, dt=0
        vf[0][1] = *(const short8*)(Vq + 4096);     // i=1: kc=0, dt=1
        vf[1][0] = *(const short8*)(Vq + 8192);     // i=2: kc=0, dt=2
        vf[1][1] = *(const short8*)(Vq + 12288);    // i=3: kc=0, dt=3
        // lane-partial sum tree (cross-half shfl deferred to after the loop)
        float s0 = ((acc0[0]+acc0[1])+(acc0[2]+acc0[3]))
                 + ((acc0[4]+acc0[5])+(acc0[6]+acc0[7]));
        float s1 = ((acc0[8]+acc0[9])+(acc0[10]+acc0[11]))
                 + ((acc0[12]+acc0[13])+(acc0[14]+acc0[15]));
        float s2 = ((acc1[0]+acc1[1])+(acc1[2]+acc1[3]))
                 + ((acc1[4]+acc1[5])+(acc1[6]+acc1[7]));
        float s3 = ((acc1[8]+acc1[9])+(acc1[10]+acc1[11]))
                 + ((acc1[12]+acc1[13])+(acc1[14]+acc1[15]));
        lsum += (s0 + s1) + (s2 + s3);

        // ---- O^T += V^T P^T, rotating prefetch (2 read-pairs in flight) ----
        // Linear order i = kc*4+dt: vf for step s+2 issued at step s.
        __builtin_amdgcn_s_setprio(1);
        #pragma unroll
        for (int s = 0; s < 8; ++s) {
            if (s < 6) {
                int i0 = 2 * s + 4, i1 = 2 * s + 5;
                uintptr_t aA = (Vq ^ (uint)((i0 >> 2) * 32)) + (uint)((i0 & 3) * 4096);
                uintptr_t aB = (Vq ^ (uint)((i1 >> 2) * 32)) + (uint)((i1 & 3) * 4096);
                vf[(s + 2) % 3][0] = *(const short8*)aA;
                vf[(s + 2) % 3][1] = *(const short8*)aB;
            }
            o[(2 * s) & 3] = __builtin_amdgcn_mfma_f32_32x32x16_bf16(
                vf[s % 3][0], pf[(2 * s) >> 2], o[(2 * s) & 3], 0, 0, 0);
            o[(2 * s + 1) & 3] = __builtin_amdgcn_mfma_f32_32x32x16_bf16(
                vf[s % 3][1], pf[(2 * s + 1) >> 2], o[(2 * s + 1) & 3], 0, 0, 0);
        }
        __builtin_amdgcn_s_setprio(0);

        __syncthreads();     // reads of buf[cur] done + DMA into buf[cur^1] drained
        cur ^= 1;
    }

    // Complete the cross-half lsum reduction once (exact: halves share m).
    lsum += __shfl_xor(lsum, 32);

    // ---- merge halves through LDS, residual-fused transposed writeout ----
    if (half == 1) {
        float* obuf = (float*)(smem + ww * 16384);
        #pragma unroll
        for (int dt = 0; dt < 4; ++dt)
            #pragma unroll
            for (int r = 0; r < 16; ++r) {
                int dl = dt * 32 + (r & 3) + 8 * (r >> 2) + 4 * hi;
                obuf[dl * 32 + q] = o[dt][r];
            }
        if (hi == 0) {
            float* ml = (float*)(smem + 65536 + ww * 256);
            ml[q * 2]     = m;
            ml[q * 2 + 1] = lsum;
        }
    }
    __syncthreads();
    if (half == 0) {
        const float* obuf = (const float*)(smem + ww * 16384);
        const float* ml   = (const float*)(smem + 65536 + ww * 256);
        float m2 = ml[q * 2], l2 = ml[q * 2 + 1];
        float M  = fmaxf(m, m2);
        float c1 = EXP2F(m - M), c2 = EXP2F(m2 - M);
        float inv = 1.0f / (lsum * c1 + l2 * c2);
        const float* xb = x   + (size_t)b * D_ * S_;
        float*       ob = out + (size_t)b * D_ * S_;
        int s = q0 + ww * 32 + q;
        #pragma unroll
        for (int dt = 0; dt < 4; ++dt)
            #pragma unroll
            for (int r = 0; r < 16; ++r) {
                int dl = dt * 32 + (r & 3) + 8 * (r >> 2) + 4 * hi;
                float val = (o[dt][r] * c1 + obuf[dl * 32 + q] * c2) * inv;
                size_t g = (size_t)dl * S_ + s;
                ob[g] = xb[g] + val;
            }
    }
}

extern "C" void kernel_launch(void* const* d_in, const int* in_sizes, int n_in,
                              void* d_out, int out_size, void* d_ws, size_t ws_size,
                              hipStream_t stream) {
    const float* x  = (const float*)d_in[0];
    const float* Wq = (const float*)d_in[1];
    const float* bq = (const float*)d_in[2];
    const float* Wk = (const float*)d_in[3];
    const float* bk = (const float*)d_in[4];
    const float* Wv = (const float*)d_in[5];
    const float* bv = (const float*)d_in[6];
    float* out = (float*)d_out;

    size_t n = (size_t)B_ * S_ * D_;
    short* Qw = (short*)d_ws;
    short* Kw = Qw + n;
    short* Vw = Kw + n;
    short* Wf = (short*)d_out;   // scratch at head of d_out; fully overwritten

    wpack_kernel<<<24, 256, 0, stream>>>(Wq, Wk, Wv, Wf);

    dim3 grid(S_ / 64, B_);
    qkv_kernel<<<grid, 256, 0, stream>>>(x, Wf, bq, bk, bv, Qw, Kw, Vw);

    int smemB = 131072;
    (void)hipFuncSetAttribute((const void*)attn_kernel,
                              hipFuncAttributeMaxDynamicSharedMemorySize, smemB);
    attn_kernel<<<256, 512, smemB, stream>>>(Qw, Kw, Vw, x, out);
}

// Round 12
// 127.821 us; speedup vs baseline: 1.1087x; 1.1087x over previous
//
#include <hip/hip_runtime.h>
#include <hip/hip_bf16.h>

#define B_ 8
#define D_ 128
#define S_ 4096

typedef short short8 __attribute__((ext_vector_type(8)));
typedef float f32x4  __attribute__((ext_vector_type(4)));
typedef float f32x16 __attribute__((ext_vector_type(16)));
typedef unsigned int uint;
typedef uint uint4v __attribute__((ext_vector_type(4)));

#define EXP2F(x) exp2f(x)

__device__ __forceinline__ short f2bf(float f) {
    __hip_bfloat16 h = __float2bfloat16(f);
    return *reinterpret_cast<short*>(&h);
}

// pack two f32 -> one u32 of 2 bf16 (elem0 = lo word)
__device__ __forceinline__ uint cvtpk(float lo, float hi) {
    uint r;
    asm("v_cvt_pk_bf16_f32 %0, %1, %2" : "=v"(r) : "v"(lo), "v"(hi));
    return r;
}

// async global->LDS DMA, 16B/lane; LDS dest = wave-uniform base + lane*16
__device__ __forceinline__ void gload16(const void* g, void* l) {
    __builtin_amdgcn_global_load_lds(
        (const __attribute__((address_space(1))) void*)g,
        (__attribute__((address_space(3))) void*)l, 16, 0, 0);
}

__device__ __forceinline__ float max3f(float a, float b, float c) {
    return fmaxf(fmaxf(a, b), c);    // clang fuses to v_max3_f32
}

// ---------------------------------------------------------------------------
// Kernel 0: pack Wq/Wk/Wv into bf16 MFMA fragments (16x16x32 layout for qkv).
// ---------------------------------------------------------------------------
__global__ __launch_bounds__(256) void wpack_kernel(
    const float* __restrict__ Wq, const float* __restrict__ Wk,
    const float* __restrict__ Wv, short* __restrict__ Wf)
{
    int g = blockIdx.x * 256 + threadIdx.x;      // 0..6143
    int lane = g & 63, kc = (g >> 6) & 3, n = (g >> 8) & 7, wm = g >> 11;
    const float* W = (wm == 0) ? Wq : (wm == 1) ? Wk : Wv;
    int row = n * 16 + (lane & 15);
    int col = kc * 32 + (lane >> 4) * 8;
    short8 o;
    #pragma unroll
    for (int j = 0; j < 8; ++j) o[j] = f2bf(W[row * 128 + col + j]);
    *((short8*)Wf + g) = o;
}

// ---------------------------------------------------------------------------
// Kernel 1: QKV projection via bf16 MFMA (16x16x32), unchanged.
// Q: (B,S,D) bf16 scaled by log2(e)/sqrt(D). K: (B,S,D). V: (B,D,S).
// ---------------------------------------------------------------------------
__global__ __launch_bounds__(256) void qkv_kernel(
    const float* __restrict__ x, const short* __restrict__ Wf,
    const float* __restrict__ bq, const float* __restrict__ bk,
    const float* __restrict__ bv,
    short* __restrict__ Qo, short* __restrict__ Ko, short* __restrict__ Vo)
{
    __shared__ float xt[64 * 132];
    const int b  = blockIdx.y;
    const int s0 = blockIdx.x * 64;
    const int t  = threadIdx.x;
    const int w    = t >> 6;
    const int lane = t & 63;
    const int lr   = lane & 15;
    const int lg   = lane >> 4;

    const float* xb = x + (size_t)b * D_ * S_;
    #pragma unroll
    for (int it = 0; it < 32; ++it) {
        int d = it * 4 + (t >> 6);
        int s = t & 63;
        xt[s * 132 + d] = xb[(size_t)d * S_ + s0 + s];
    }
    __syncthreads();

    short8 xtf[4];
    {
        const float* base = &xt[(w * 16 + lr) * 132 + lg * 8];
        #pragma unroll
        for (int kc = 0; kc < 4; ++kc) {
            float4 a = *(const float4*)(base + kc * 32);
            float4 c = *(const float4*)(base + kc * 32 + 4);
            short8 f;
            f[0] = f2bf(a.x); f[1] = f2bf(a.y); f[2] = f2bf(a.z); f[3] = f2bf(a.w);
            f[4] = f2bf(c.x); f[5] = f2bf(c.y); f[6] = f2bf(c.z); f[7] = f2bf(c.w);
            xtf[kc] = f;
        }
    }

    const float qs = 0.08838834764831845f * 1.4426950408889634f;
    const short8* W8 = (const short8*)Wf;
    const size_t bSD = (size_t)b * S_ * D_;
    const size_t bDS = (size_t)b * D_ * S_;

    #pragma unroll
    for (int n = 0; n < 8; ++n) {
        f32x4 aq = (f32x4){0.f, 0.f, 0.f, 0.f};
        f32x4 ak = (f32x4){0.f, 0.f, 0.f, 0.f};
        f32x4 av = (f32x4){0.f, 0.f, 0.f, 0.f};
        #pragma unroll
        for (int kc = 0; kc < 4; ++kc) {
            short8 wq = W8[(      n * 4 + kc) * 64 + lane];
            short8 wk = W8[(32  + n * 4 + kc) * 64 + lane];
            short8 wv = W8[(64  + n * 4 + kc) * 64 + lane];
            aq = __builtin_amdgcn_mfma_f32_16x16x32_bf16(xtf[kc], wq, aq, 0, 0, 0);
            ak = __builtin_amdgcn_mfma_f32_16x16x32_bf16(xtf[kc], wk, ak, 0, 0, 0);
            av = __builtin_amdgcn_mfma_f32_16x16x32_bf16(wv, xtf[kc], av, 0, 0, 0);
        }
        int e = n * 16 + lr;
        float bqe = bq[e], bke = bk[e];
        #pragma unroll
        for (int r = 0; r < 4; ++r) {
            size_t off = (bSD + (size_t)(s0 + w * 16 + lg * 4 + r) * D_) + e;
            Qo[off] = f2bf((aq[r] + bqe) * qs);
            Ko[off] = f2bf(ak[r] + bke);
        }
        #pragma unroll
        for (int r = 0; r < 4; ++r) {
            int ev = n * 16 + lg * 4 + r;
            Vo[bDS + (size_t)ev * S_ + s0 + w * 16 + lr] = f2bf(av[r] + bv[ev]);
        }
    }
}

// ---------------------------------------------------------------------------
// Kernel 2: flash attention (R9 base) + acc-carry pipeline with T19
// sched_group_barrier pinning: interval t runs [part1(t); {QK(t+1) || 
// exp/pack(t)} SGB-interleaved; PV(t)+sums]. K TRIPLE-buffered (QK(t+1)
// reads a tile staged one interval earlier, visible via the interval-(t-1)
// barrier); V double-buffered. LDS = 96K K + 64K V = 160 KiB exactly.
// SGB template per c-step: {DS_READ x2, MFMA x2, VALU x8} -- the region's
// 16 K-reads, 16 QK MFMAs, and 64 exp/sub VALU ops. No setprio around QK
// (fence would kill the region); setprio kept on PV only.
// R11 lesson: array-indexed LDS addressing (compiler-folded ds offsets)
// restored everywhere; no pointer-cast XOR tricks.
// C/D layout (m74/m101): col=lane&31, row=(reg&3)+8*(reg>>2)+4*(lane>>5).
// ---------------------------------------------------------------------------
__global__ __launch_bounds__(512, 2) void attn_kernel(
    const short* __restrict__ Q, const short* __restrict__ K,
    const short* __restrict__ Vt, const float* __restrict__ x,
    float* __restrict__ out)
{
    extern __shared__ __align__(16) char smem[];   // 163840 B
    const int lin = blockIdx.x;
    const int b   = lin & 7;            // XCD swizzle: one b per XCD
    const int q0  = (lin >> 3) * 128;
    const int tid  = threadIdx.x;
    const int w    = tid >> 6;
    const int lane = tid & 63;
    const int q    = lane & 31;         // this lane's q column
    const int hi   = lane >> 5;
    const int half = w >> 2;            // KV half: kt 0..31 -> rows half*2048..
    const int ww   = w & 3;             // q strip (q0 + ww*32 ..)

    const size_t bSD = (size_t)b * S_ * D_;

    // Q fragments: qf[c][j] = Q[q0+ww*32+q][c*16 + hi*8 + j]
    short8 qf[8];
    {
        const short* Qrow = Q + bSD + (size_t)(q0 + ww * 32 + q) * D_ + hi * 8;
        #pragma unroll
        for (int c = 0; c < 8; ++c)
            qf[c] = *(const short8*)(Qrow + c * 16);
    }

    f32x16 o[4];
    #pragma unroll
    for (int dt = 0; dt < 4; ++dt)
        #pragma unroll
        for (int i = 0; i < 16; ++i) o[dt][i] = 0.f;
    float m = -1e30f, lsum = 0.f;      // lsum LANE-PARTIAL until after loop

    const short* Kb = K + bSD;
    const short* Vb = Vt + (size_t)b * D_ * S_;
    const int ktbase = half * 32;

    // LDS: K [3 buf][2 half][16KB] at 0; V [2 buf][2 half][16KB] at 98304.
    auto KH = [&](int t) -> const char* {
        return smem + ((t % 3) * 2 + half) * 16384;
    };
    auto VH = [&](int t) -> const char* {
        return smem + 98304 + ((t & 1) * 2 + half) * 16384;
    };

    // DMA staging (linear LDS dest; global src pre-swizzled: phys 16B-chunk c
    // of row r holds logical chunk c^(r&7)).
    auto stageK = [&](int kt) {
        const short* Kg = Kb + (size_t)(ktbase + kt) * 64 * D_;
        char* Kd = smem + ((kt % 3) * 2 + half) * 16384;
        #pragma unroll
        for (int i = 0; i < 4; ++i) {
            int ki = ww * 4 + i;                 // 1KB chunk: rows 4ki..4ki+3
            int r  = ki * 4 + (lane >> 4);
            gload16(Kg + r * D_ + (((lane & 15) ^ (r & 7)) * 8), Kd + ki * 1024);
        }
    };
    auto stageV = [&](int kt) {
        const short* Vg = Vb + (size_t)(ktbase + kt) * 64;
        char* Vd = smem + 98304 + ((kt & 1) * 2 + half) * 16384;
        #pragma unroll
        for (int i = 0; i < 4; ++i) {
            int vi = ww * 4 + i;                 // 1KB chunk: rows 8vi..8vi+7
            int r  = vi * 8 + (lane >> 3);
            gload16(Vg + (size_t)r * S_ + (((lane & 7) ^ (lane >> 3)) * 8),
                    Vd + vi * 1024);
        }
    };

    // S^T = K Q^T with depth-2-pair rotating prefetch. NO setprio (must stay
    // schedulable against the exp/pack VALU in the same region).
    auto qkrun = [&](const char* Kh, f32x16& A0, f32x16& A1) {
        #pragma unroll
        for (int i = 0; i < 16; ++i) { A0[i] = 0.f; A1[i] = 0.f; }
        short8 kf[3][2];
        {
            int co0 = ((0 + hi) ^ (q & 7)) * 16;
            int co1 = ((2 + hi) ^ (q & 7)) * 16;
            kf[0][0] = *(const short8*)(Kh + q * 256 + co0);
            kf[0][1] = *(const short8*)(Kh + (32 + q) * 256 + co0);
            kf[1][0] = *(const short8*)(Kh + q * 256 + co1);
            kf[1][1] = *(const short8*)(Kh + (32 + q) * 256 + co1);
        }
        #pragma unroll
        for (int c = 0; c < 8; ++c) {
            if (c < 6) {
                int co = (((c + 2) * 2 + hi) ^ (q & 7)) * 16;
                kf[(c + 2) % 3][0] = *(const short8*)(Kh + q * 256 + co);
                kf[(c + 2) % 3][1] = *(const short8*)(Kh + (32 + q) * 256 + co);
            }
            A0 = __builtin_amdgcn_mfma_f32_32x32x16_bf16(kf[c % 3][0], qf[c], A0, 0, 0, 0);
            A1 = __builtin_amdgcn_mfma_f32_32x32x16_bf16(kf[c % 3][1], qf[c], A1, 0, 0, 0);
        }
    };

    // part1: tile max (v_max3 tree), cross-half max, T13 gate + rescale.
    auto part1 = [&](const f32x16& A0, const f32x16& A1) {
        float a0 = max3f(A0[0],  A0[1],  A0[2]);
        float a1 = max3f(A0[3],  A0[4],  A0[5]);
        float a2 = max3f(A0[6],  A0[7],  A0[8]);
        float a3 = max3f(A0[9],  A0[10], A0[11]);
        float a4 = max3f(A0[12], A0[13], A0[14]);
        float a5 = max3f(A1[0],  A1[1],  A1[2]);
        float a6 = max3f(A1[3],  A1[4],  A1[5]);
        float a7 = max3f(A1[6],  A1[7],  A1[8]);
        float a8 = max3f(A1[9],  A1[10], A1[11]);
        float a9 = max3f(A1[12], A1[13], A1[14]);
        float b0 = max3f(a0, a1, a2);
        float b1 = max3f(a3, a4, A0[15]);
        float b2 = max3f(a5, a6, a7);
        float b3 = max3f(a8, a9, A1[15]);
        float tm = fmaxf(max3f(b0, b1, b2), b3);
        tm = fmaxf(tm, __shfl_xor(tm, 32));
        if (!__all(tm <= m + 8.f)) {
            float mn   = fmaxf(m, tm);
            float corr = EXP2F(m - mn);
            m = mn; lsum *= corr;
            #pragma unroll
            for (int dt = 0; dt < 4; ++dt)
                #pragma unroll
                for (int r = 0; r < 16; ++r) o[dt][r] *= corr;
        }
    };

    // exp + P-pack (the VALU that SGB interleaves with QK(t+1)).
    auto exppack = [&](f32x16& A0, f32x16& A1, short8* pf) {
        #pragma unroll
        for (int r = 0; r < 16; ++r) A0[r] = EXP2F(A0[r] - m);
        #pragma unroll
        for (int r = 0; r < 16; ++r) A1[r] = EXP2F(A1[r] - m);
        #pragma unroll
        for (int kc = 0; kc < 4; ++kc) {
            const f32x16& a = (kc < 2) ? A0 : A1;
            int c1 = (kc & 1) * 8;
            uint W0 = cvtpk(a[c1 + 0], a[c1 + 1]);
            uint W1 = cvtpk(a[c1 + 2], a[c1 + 3]);
            uint W2 = cvtpk(a[c1 + 4], a[c1 + 5]);
            uint W3 = cvtpk(a[c1 + 6], a[c1 + 7]);
            asm("v_permlane32_swap_b32 %0, %1" : "+v"(W0), "+v"(W2));
            asm("v_permlane32_swap_b32 %0, %1" : "+v"(W1), "+v"(W3));
            uint4v pw;
            pw.x = W0; pw.y = W1; pw.z = W2; pw.w = W3;
            pf[kc] = *reinterpret_cast<short8*>(&pw);
        }
    };

    // T19 template: per c-step {2 ds_read, 2 MFMA, 8 VALU}.
    auto sgb = [&]() {
        #pragma unroll
        for (int s8 = 0; s8 < 8; ++s8) {
            __builtin_amdgcn_sched_group_barrier(0x100, 2, 0);  // DS_READ
            __builtin_amdgcn_sched_group_barrier(0x008, 2, 0);  // MFMA
            __builtin_amdgcn_sched_group_barrier(0x002, 8, 0);  // VALU
        }
    };

    // V prefetch + lane-partial sums + PV (R9's structure).
    auto pvrun = [&](const f32x16& A0, const f32x16& A1,
                     const short8* pf, const char* Vh) {
        short8 vf[3][2];
        {
            int co0 = ((0 + hi) ^ (q & 7)) * 16;
            vf[0][0] = *(const short8*)(Vh + (0 * 32 + q) * 128 + co0);
            vf[0][1] = *(const short8*)(Vh + (1 * 32 + q) * 128 + co0);
            vf[1][0] = *(const short8*)(Vh + (2 * 32 + q) * 128 + co0);
            vf[1][1] = *(const short8*)(Vh + (3 * 32 + q) * 128 + co0);
        }
        float s0 = ((A0[0]+A0[1])+(A0[2]+A0[3])) + ((A0[4]+A0[5])+(A0[6]+A0[7]));
        float s1 = ((A0[8]+A0[9])+(A0[10]+A0[11])) + ((A0[12]+A0[13])+(A0[14]+A0[15]));
        float s2 = ((A1[0]+A1[1])+(A1[2]+A1[3])) + ((A1[4]+A1[5])+(A1[6]+A1[7]));
        float s3 = ((A1[8]+A1[9])+(A1[10]+A1[11])) + ((A1[12]+A1[13])+(A1[14]+A1[15]));
        lsum += (s0 + s1) + (s2 + s3);

        __builtin_amdgcn_s_setprio(1);
        #pragma unroll
        for (int s = 0; s < 8; ++s) {
            if (s < 6) {
                int i0 = 2 * s + 4, i1 = 2 * s + 5;
                int coA = (((i0 >> 2) * 2 + hi) ^ (q & 7)) * 16;
                int coB = (((i1 >> 2) * 2 + hi) ^ (q & 7)) * 16;
                vf[(s + 2) % 3][0] = *(const short8*)(Vh + ((i0 & 3) * 32 + q) * 128 + coA);
                vf[(s + 2) % 3][1] = *(const short8*)(Vh + ((i1 & 3) * 32 + q) * 128 + coB);
            }
            o[(2 * s) & 3] = __builtin_amdgcn_mfma_f32_32x32x16_bf16(
                vf[s % 3][0], pf[(2 * s) >> 2], o[(2 * s) & 3], 0, 0, 0);
            o[(2 * s + 1) & 3] = __builtin_amdgcn_mfma_f32_32x32x16_bf16(
                vf[s % 3][1], pf[(2 * s + 1) >> 2], o[(2 * s + 1) & 3], 0, 0, 0);
        }
        __builtin_amdgcn_s_setprio(0);
    };

    f32x16 aA0, aA1, aB0, aB1;

    // Prologue: K0,V0,K1 staged; QK(0) -> accA. (3-buf K: no extra barrier,
    // interval-0 staging targets buf2, disjoint from buf0 being read.)
    stageK(0); stageV(0); stageK(1);
    __syncthreads();
    qkrun(KH(0), aA0, aA1);

    // Hot loop: tiles 0..29 (2-unrolled, branch-free bodies).
    for (int t = 0; t < 30; t += 2) {
        // even body: consume A (tile t), produce B (tile t+1)
        stageK(t + 2); stageV(t + 1);
        part1(aA0, aA1);
        {
            short8 pf[4];
            qkrun(KH(t + 1), aB0, aB1);
            exppack(aA0, aA1, pf);
            sgb();
            pvrun(aA0, aA1, pf, VH(t));
        }
        __syncthreads();
        // odd body: consume B (tile t+1), produce A (tile t+2)
        stageK(t + 3); stageV(t + 2);
        part1(aB0, aB1);
        {
            short8 pf[4];
            qkrun(KH(t + 2), aA0, aA1);
            exppack(aB0, aB1, pf);
            sgb();
            pvrun(aB0, aB1, pf, VH(t + 1));
        }
        __syncthreads();
    }
    // Interval 30: stage V(31); QK(31); finish tile 30.
    stageV(31);
    part1(aA0, aA1);
    {
        short8 pf[4];
        qkrun(KH(31), aB0, aB1);
        exppack(aA0, aA1, pf);
        sgb();
        pvrun(aA0, aA1, pf, VH(30));
    }
    __syncthreads();
    // Interval 31: finish tile 31 (no QK, no stage).
    part1(aB0, aB1);
    {
        short8 pf[4];
        exppack(aB0, aB1, pf);
        pvrun(aB0, aB1, pf, VH(31));
    }

    // Complete the cross-half lsum reduction once (exact: halves share m).
    lsum += __shfl_xor(lsum, 32);

    // ---- merge halves through LDS, residual-fused transposed writeout ----
    // obuf in dead K region [0,64K); ml in dead V buf0 region (PV(31) read
    // vbuf1). All K reads ended at the interval-30 barrier.
    if (half == 1) {
        float* obuf = (float*)(smem + ww * 16384);
        #pragma unroll
        for (int dt = 0; dt < 4; ++dt)
            #pragma unroll
            for (int r = 0; r < 16; ++r) {
                int dl = dt * 32 + (r & 3) + 8 * (r >> 2) + 4 * hi;
                obuf[dl * 32 + q] = o[dt][r];
            }
        if (hi == 0) {
            float* ml = (float*)(smem + 98304 + ww * 256);
            ml[q * 2]     = m;
            ml[q * 2 + 1] = lsum;
        }
    }
    __syncthreads();
    if (half == 0) {
        const float* obuf = (const float*)(smem + ww * 16384);
        const float* ml   = (const float*)(smem + 98304 + ww * 256);
        float m2 = ml[q * 2], l2 = ml[q * 2 + 1];
        float M  = fmaxf(m, m2);
        float c1 = EXP2F(m - M), c2 = EXP2F(m2 - M);
        float inv = 1.0f / (lsum * c1 + l2 * c2);
        const float* xb = x   + (size_t)b * D_ * S_;
        float*       ob = out + (size_t)b * D_ * S_;
        int s = q0 + ww * 32 + q;
        #pragma unroll
        for (int dt = 0; dt < 4; ++dt)
            #pragma unroll
            for (int r = 0; r < 16; ++r) {
                int dl = dt * 32 + (r & 3) + 8 * (r >> 2) + 4 * hi;
                float val = (o[dt][r] * c1 + obuf[dl * 32 + q] * c2) * inv;
                size_t g = (size_t)dl * S_ + s;
                ob[g] = xb[g] + val;
            }
    }
}

extern "C" void kernel_launch(void* const* d_in, const int* in_sizes, int n_in,
                              void* d_out, int out_size, void* d_ws, size_t ws_size,
                              hipStream_t stream) {
    const float* x  = (const float*)d_in[0];
    const float* Wq = (const float*)d_in[1];
    const float* bq = (const float*)d_in[2];
    const float* Wk = (const float*)d_in[3];
    const float* bk = (const float*)d_in[4];
    const float* Wv = (const float*)d_in[5];
    const float* bv = (const float*)d_in[6];
    float* out = (float*)d_out;

    size_t n = (size_t)B_ * S_ * D_;
    short* Qw = (short*)d_ws;
    short* Kw = Qw + n;
    short* Vw = Kw + n;
    short* Wf = (short*)d_out;   // scratch at head of d_out; fully overwritten

    wpack_kernel<<<24, 256, 0, stream>>>(Wq, Wk, Wv, Wf);

    dim3 grid(S_ / 64, B_);
    qkv_kernel<<<grid, 256, 0, stream>>>(x, Wf, bq, bk, bv, Qw, Kw, Vw);

    int smemB = 163840;
    (void)hipFuncSetAttribute((const void*)attn_kernel,
                              hipFuncAttributeMaxDynamicSharedMemorySize, smemB);
    attn_kernel<<<256, 512, smemB, stream>>>(Qw, Kw, Vw, x, out);
}

// Round 13
// 118.277 us; speedup vs baseline: 1.1982x; 1.0807x over previous
//
#include <hip/hip_runtime.h>
#include <hip/hip_bf16.h>

#define B_ 8
#define D_ 128
#define S_ 4096

typedef short short8 __attribute__((ext_vector_type(8)));
typedef float f32x4  __attribute__((ext_vector_type(4)));
typedef float f32x16 __attribute__((ext_vector_type(16)));
typedef unsigned int uint;
typedef uint uint4v __attribute__((ext_vector_type(4)));

#define EXP2F(x) exp2f(x)

__device__ __forceinline__ short f2bf(float f) {
    __hip_bfloat16 h = __float2bfloat16(f);
    return *reinterpret_cast<short*>(&h);
}

// pack two f32 -> one u32 of 2 bf16 (elem0 = lo word)
__device__ __forceinline__ uint cvtpk(float lo, float hi) {
    uint r;
    asm("v_cvt_pk_bf16_f32 %0, %1, %2" : "=v"(r) : "v"(lo), "v"(hi));
    return r;
}

// async global->LDS DMA, 16B/lane; LDS dest = wave-uniform base + lane*16
__device__ __forceinline__ void gload16(const void* g, void* l) {
    __builtin_amdgcn_global_load_lds(
        (const __attribute__((address_space(1))) void*)g,
        (__attribute__((address_space(3))) void*)l, 16, 0, 0);
}

__device__ __forceinline__ float max3f(float a, float b, float c) {
    return fmaxf(fmaxf(a, b), c);    // clang fuses to v_max3_f32
}

// ---------------------------------------------------------------------------
// Kernel 0: pack Wq/Wk/Wv into bf16 MFMA fragments (16x16x32 layout for qkv).
// ---------------------------------------------------------------------------
__global__ __launch_bounds__(256) void wpack_kernel(
    const float* __restrict__ Wq, const float* __restrict__ Wk,
    const float* __restrict__ Wv, short* __restrict__ Wf)
{
    int g = blockIdx.x * 256 + threadIdx.x;      // 0..6143
    int lane = g & 63, kc = (g >> 6) & 3, n = (g >> 8) & 7, wm = g >> 11;
    const float* W = (wm == 0) ? Wq : (wm == 1) ? Wk : Wv;
    int row = n * 16 + (lane & 15);
    int col = kc * 32 + (lane >> 4) * 8;
    short8 o;
    #pragma unroll
    for (int j = 0; j < 8; ++j) o[j] = f2bf(W[row * 128 + col + j]);
    *((short8*)Wf + g) = o;
}

// ---------------------------------------------------------------------------
// Kernel 1: QKV projection via bf16 MFMA (16x16x32), unchanged.
// Q: (B,S,D) bf16 scaled by log2(e)/sqrt(D). K: (B,S,D). V: (B,D,S).
// ---------------------------------------------------------------------------
__global__ __launch_bounds__(256) void qkv_kernel(
    const float* __restrict__ x, const short* __restrict__ Wf,
    const float* __restrict__ bq, const float* __restrict__ bk,
    const float* __restrict__ bv,
    short* __restrict__ Qo, short* __restrict__ Ko, short* __restrict__ Vo)
{
    __shared__ float xt[64 * 132];
    const int b  = blockIdx.y;
    const int s0 = blockIdx.x * 64;
    const int t  = threadIdx.x;
    const int w    = t >> 6;
    const int lane = t & 63;
    const int lr   = lane & 15;
    const int lg   = lane >> 4;

    const float* xb = x + (size_t)b * D_ * S_;
    #pragma unroll
    for (int it = 0; it < 32; ++it) {
        int d = it * 4 + (t >> 6);
        int s = t & 63;
        xt[s * 132 + d] = xb[(size_t)d * S_ + s0 + s];
    }
    __syncthreads();

    short8 xtf[4];
    {
        const float* base = &xt[(w * 16 + lr) * 132 + lg * 8];
        #pragma unroll
        for (int kc = 0; kc < 4; ++kc) {
            float4 a = *(const float4*)(base + kc * 32);
            float4 c = *(const float4*)(base + kc * 32 + 4);
            short8 f;
            f[0] = f2bf(a.x); f[1] = f2bf(a.y); f[2] = f2bf(a.z); f[3] = f2bf(a.w);
            f[4] = f2bf(c.x); f[5] = f2bf(c.y); f[6] = f2bf(c.z); f[7] = f2bf(c.w);
            xtf[kc] = f;
        }
    }

    const float qs = 0.08838834764831845f * 1.4426950408889634f;
    const short8* W8 = (const short8*)Wf;
    const size_t bSD = (size_t)b * S_ * D_;
    const size_t bDS = (size_t)b * D_ * S_;

    #pragma unroll
    for (int n = 0; n < 8; ++n) {
        f32x4 aq = (f32x4){0.f, 0.f, 0.f, 0.f};
        f32x4 ak = (f32x4){0.f, 0.f, 0.f, 0.f};
        f32x4 av = (f32x4){0.f, 0.f, 0.f, 0.f};
        #pragma unroll
        for (int kc = 0; kc < 4; ++kc) {
            short8 wq = W8[(      n * 4 + kc) * 64 + lane];
            short8 wk = W8[(32  + n * 4 + kc) * 64 + lane];
            short8 wv = W8[(64  + n * 4 + kc) * 64 + lane];
            aq = __builtin_amdgcn_mfma_f32_16x16x32_bf16(xtf[kc], wq, aq, 0, 0, 0);
            ak = __builtin_amdgcn_mfma_f32_16x16x32_bf16(xtf[kc], wk, ak, 0, 0, 0);
            av = __builtin_amdgcn_mfma_f32_16x16x32_bf16(wv, xtf[kc], av, 0, 0, 0);
        }
        int e = n * 16 + lr;
        float bqe = bq[e], bke = bk[e];
        #pragma unroll
        for (int r = 0; r < 4; ++r) {
            size_t off = (bSD + (size_t)(s0 + w * 16 + lg * 4 + r) * D_) + e;
            Qo[off] = f2bf((aq[r] + bqe) * qs);
            Ko[off] = f2bf(ak[r] + bke);
        }
        #pragma unroll
        for (int r = 0; r < 4; ++r) {
            int ev = n * 16 + lg * 4 + r;
            Vo[bDS + (size_t)ev * S_ + s0 + w * 16 + lr] = f2bf(av[r] + bv[ev]);
        }
    }
}

// ---------------------------------------------------------------------------
// Kernel 2: flash attention (R9, the measured best: 113.7-118 us).
// 512 thr = 2 KV-halves x 4 q-strips, 64-kv tiles, K+V DMA-staged,
// double-buffered, 1 barrier/tile; depth-2-pair rotating LDS-read prefetch
// in QK and PV; lane-partial lsum (single cross-half shfl after the loop);
// sum-tree placed after P-pack + V-prefetch (hides under PV); v_max3 tree.
// 12-round exploration record: more waves (R2), private staging + direct-V
// (R3), source-order interleave (R4/R5), cross-block drift (R6), QBLK=64
// (R7), role dephasing (R10), XOR addressing (R11), SGB pipeline (R12) all
// regressed or were null -- this structure at 2 waves/SIMD is the plateau.
// C/D layout (m74/m101): col=lane&31, row=(reg&3)+8*(reg>>2)+4*(lane>>5).
// ---------------------------------------------------------------------------
__global__ __launch_bounds__(512, 2) void attn_kernel(
    const short* __restrict__ Q, const short* __restrict__ K,
    const short* __restrict__ Vt, const float* __restrict__ x,
    float* __restrict__ out)
{
    extern __shared__ __align__(16) char smem[];   // 131072 B
    const int lin = blockIdx.x;
    const int b   = lin & 7;            // XCD swizzle: one b per XCD
    const int q0  = (lin >> 3) * 128;
    const int tid  = threadIdx.x;
    const int w    = tid >> 6;
    const int lane = tid & 63;
    const int q    = lane & 31;         // this lane's q column
    const int hi   = lane >> 5;
    const int half = w >> 2;            // KV half: kt 0..31 -> rows half*2048..
    const int ww   = w & 3;             // q strip (q0 + ww*32 ..)

    const size_t bSD = (size_t)b * S_ * D_;

    // Q fragments: qf[c][j] = Q[q0+ww*32+q][c*16 + hi*8 + j]
    short8 qf[8];
    {
        const short* Qrow = Q + bSD + (size_t)(q0 + ww * 32 + q) * D_ + hi * 8;
        #pragma unroll
        for (int c = 0; c < 8; ++c)
            qf[c] = *(const short8*)(Qrow + c * 16);
    }

    f32x16 o[4];
    #pragma unroll
    for (int dt = 0; dt < 4; ++dt)
        #pragma unroll
        for (int i = 0; i < 16; ++i) o[dt][i] = 0.f;
    float m = -1e30f, lsum = 0.f;      // lsum LANE-PARTIAL until after loop

    const short* Kb = K + bSD;
    const short* Vb = Vt + (size_t)b * D_ * S_;
    const int ktbase = half * 32;

    // DMA-stage one 64-kv tile of this wave's half into buffer `buf`.
    // LDS dest linear; global src pre-swizzled (phys 16B-chunk c of row r
    // holds logical chunk c^(r&7)).
    auto stage = [&](int kt, int buf) {
        const short* Kg = Kb + (size_t)(ktbase + kt) * 64 * D_;
        const short* Vg = Vb + (size_t)(ktbase + kt) * 64;
        char* Kd = smem + buf * 65536 + half * 32768;
        char* Vd = Kd + 16384;
        #pragma unroll
        for (int i = 0; i < 4; ++i) {
            int ki = ww * 4 + i;                 // 1KB chunk: rows 4ki..4ki+3
            int r  = ki * 4 + (lane >> 4);
            gload16(Kg + r * D_ + (((lane & 15) ^ (r & 7)) * 8), Kd + ki * 1024);
        }
        #pragma unroll
        for (int i = 0; i < 4; ++i) {
            int vi = ww * 4 + i;                 // 1KB chunk: rows 8vi..8vi+7
            int r  = vi * 8 + (lane >> 3);
            gload16(Vg + (size_t)r * S_ + (((lane & 7) ^ (lane >> 3)) * 8),
                    Vd + vi * 1024);
        }
    };

    stage(0, 0);
    __syncthreads();                 // drains vmcnt -> buf0 ready
    int cur = 0;

    for (int kt = 0; kt < 32; ++kt) {
        if (kt + 1 < 32) stage(kt + 1, cur ^ 1);   // DMA overlaps compute

        const char* Kh = smem + cur * 65536 + half * 32768;
        const char* Vh = Kh + 16384;

        // ---- S^T = K Q^T : acc[n][r] = S[k = n*32+(r&3)+8*(r>>2)+4*hi][q] --
        // Depth-2-pair rotating prefetch (reads for c+2 issued at step c).
        f32x16 acc0, acc1;
        #pragma unroll
        for (int i = 0; i < 16; ++i) { acc0[i] = 0.f; acc1[i] = 0.f; }
        short8 kf[3][2];
        {
            int co0 = ((0 + hi) ^ (q & 7)) * 16;
            int co1 = ((2 + hi) ^ (q & 7)) * 16;
            kf[0][0] = *(const short8*)(Kh + q * 256 + co0);
            kf[0][1] = *(const short8*)(Kh + (32 + q) * 256 + co0);
            kf[1][0] = *(const short8*)(Kh + q * 256 + co1);
            kf[1][1] = *(const short8*)(Kh + (32 + q) * 256 + co1);
        }
        __builtin_amdgcn_s_setprio(1);
        #pragma unroll
        for (int c = 0; c < 8; ++c) {
            if (c < 6) {
                int co = (((c + 2) * 2 + hi) ^ (q & 7)) * 16;
                kf[(c + 2) % 3][0] = *(const short8*)(Kh + q * 256 + co);
                kf[(c + 2) % 3][1] = *(const short8*)(Kh + (32 + q) * 256 + co);
            }
            acc0 = __builtin_amdgcn_mfma_f32_32x32x16_bf16(kf[c % 3][0], qf[c], acc0, 0, 0, 0);
            acc1 = __builtin_amdgcn_mfma_f32_32x32x16_bf16(kf[c % 3][1], qf[c], acc1, 0, 0, 0);
        }
        __builtin_amdgcn_s_setprio(0);

        // ---- tile max: 3-ary tree (v_max3), then cross-half, T13 gate ----
        float a0 = max3f(acc0[0],  acc0[1],  acc0[2]);
        float a1 = max3f(acc0[3],  acc0[4],  acc0[5]);
        float a2 = max3f(acc0[6],  acc0[7],  acc0[8]);
        float a3 = max3f(acc0[9],  acc0[10], acc0[11]);
        float a4 = max3f(acc0[12], acc0[13], acc0[14]);
        float a5 = max3f(acc1[0],  acc1[1],  acc1[2]);
        float a6 = max3f(acc1[3],  acc1[4],  acc1[5]);
        float a7 = max3f(acc1[6],  acc1[7],  acc1[8]);
        float a8 = max3f(acc1[9],  acc1[10], acc1[11]);
        float a9 = max3f(acc1[12], acc1[13], acc1[14]);
        float b0 = max3f(a0, a1, a2);
        float b1 = max3f(a3, a4, acc0[15]);
        float b2 = max3f(a5, a6, a7);
        float b3 = max3f(a8, a9, acc1[15]);
        float tm = fmaxf(max3f(b0, b1, b2), b3);
        tm = fmaxf(tm, __shfl_xor(tm, 32));
        if (!__all(tm <= m + 8.f)) {
            float mn   = fmaxf(m, tm);
            float corr = EXP2F(m - mn);
            m = mn; lsum *= corr;
            #pragma unroll
            for (int dt = 0; dt < 4; ++dt)
                #pragma unroll
                for (int r = 0; r < 16; ++r) o[dt][r] *= corr;
        }
        #pragma unroll
        for (int r = 0; r < 16; ++r) acc0[r] = EXP2F(acc0[r] - m);
        #pragma unroll
        for (int r = 0; r < 16; ++r) acc1[r] = EXP2F(acc1[r] - m);

        // ---- P -> bf16 PV B-fragments (distinct SSA defs -> permlane safe) --
        short8 pf[4];
        #pragma unroll
        for (int kc = 0; kc < 4; ++kc) {
            const f32x16& a = (kc < 2) ? acc0 : acc1;
            int c1 = (kc & 1) * 8;
            uint W0 = cvtpk(a[c1 + 0], a[c1 + 1]);
            uint W1 = cvtpk(a[c1 + 2], a[c1 + 3]);
            uint W2 = cvtpk(a[c1 + 4], a[c1 + 5]);
            uint W3 = cvtpk(a[c1 + 6], a[c1 + 7]);
            asm("v_permlane32_swap_b32 %0, %1" : "+v"(W0), "+v"(W2));
            asm("v_permlane32_swap_b32 %0, %1" : "+v"(W1), "+v"(W3));
            uint4v pw;
            pw.x = W0; pw.y = W1; pw.z = W2; pw.w = W3;
            pf[kc] = *reinterpret_cast<short8*>(&pw);
        }

        // ---- V prefetch (2 pairs), then sums (hide under PV), then PV ----
        short8 vf[3][2];
        {
            int co0 = ((0 + hi) ^ (q & 7)) * 16;     // kc=0 for i=0,1
            vf[0][0] = *(const short8*)(Vh + (0 * 32 + q) * 128 + co0);
            vf[0][1] = *(const short8*)(Vh + (1 * 32 + q) * 128 + co0);
            vf[1][0] = *(const short8*)(Vh + (2 * 32 + q) * 128 + co0);
            vf[1][1] = *(const short8*)(Vh + (3 * 32 + q) * 128 + co0);
        }
        // lane-partial sum tree (cross-half shfl deferred to after the loop)
        float s0 = ((acc0[0]+acc0[1])+(acc0[2]+acc0[3]))
                 + ((acc0[4]+acc0[5])+(acc0[6]+acc0[7]));
        float s1 = ((acc0[8]+acc0[9])+(acc0[10]+acc0[11]))
                 + ((acc0[12]+acc0[13])+(acc0[14]+acc0[15]));
        float s2 = ((acc1[0]+acc1[1])+(acc1[2]+acc1[3]))
                 + ((acc1[4]+acc1[5])+(acc1[6]+acc1[7]));
        float s3 = ((acc1[8]+acc1[9])+(acc1[10]+acc1[11]))
                 + ((acc1[12]+acc1[13])+(acc1[14]+acc1[15]));
        lsum += (s0 + s1) + (s2 + s3);

        // ---- O^T += V^T P^T, rotating prefetch (2 read-pairs in flight) ----
        // Linear order i = kc*4+dt: vf for step s+2 issued at step s.
        __builtin_amdgcn_s_setprio(1);
        #pragma unroll
        for (int s = 0; s < 8; ++s) {
            if (s < 6) {
                int i0 = 2 * s + 4, i1 = 2 * s + 5;
                int coA = (((i0 >> 2) * 2 + hi) ^ (q & 7)) * 16;
                int coB = (((i1 >> 2) * 2 + hi) ^ (q & 7)) * 16;
                vf[(s + 2) % 3][0] = *(const short8*)(Vh + ((i0 & 3) * 32 + q) * 128 + coA);
                vf[(s + 2) % 3][1] = *(const short8*)(Vh + ((i1 & 3) * 32 + q) * 128 + coB);
            }
            o[(2 * s) & 3] = __builtin_amdgcn_mfma_f32_32x32x16_bf16(
                vf[s % 3][0], pf[(2 * s) >> 2], o[(2 * s) & 3], 0, 0, 0);
            o[(2 * s + 1) & 3] = __builtin_amdgcn_mfma_f32_32x32x16_bf16(
                vf[s % 3][1], pf[(2 * s + 1) >> 2], o[(2 * s + 1) & 3], 0, 0, 0);
        }
        __builtin_amdgcn_s_setprio(0);

        __syncthreads();     // reads of buf[cur] done + DMA into buf[cur^1] drained
        cur ^= 1;
    }

    // Complete the cross-half lsum reduction once (exact: halves share m).
    lsum += __shfl_xor(lsum, 32);

    // ---- merge halves through LDS, residual-fused transposed writeout ----
    if (half == 1) {
        float* obuf = (float*)(smem + ww * 16384);
        #pragma unroll
        for (int dt = 0; dt < 4; ++dt)
            #pragma unroll
            for (int r = 0; r < 16; ++r) {
                int dl = dt * 32 + (r & 3) + 8 * (r >> 2) + 4 * hi;
                obuf[dl * 32 + q] = o[dt][r];
            }
        if (hi == 0) {
            float* ml = (float*)(smem + 65536 + ww * 256);
            ml[q * 2]     = m;
            ml[q * 2 + 1] = lsum;
        }
    }
    __syncthreads();
    if (half == 0) {
        const float* obuf = (const float*)(smem + ww * 16384);
        const float* ml   = (const float*)(smem + 65536 + ww * 256);
        float m2 = ml[q * 2], l2 = ml[q * 2 + 1];
        float M  = fmaxf(m, m2);
        float c1 = EXP2F(m - M), c2 = EXP2F(m2 - M);
        float inv = 1.0f / (lsum * c1 + l2 * c2);
        const float* xb = x   + (size_t)b * D_ * S_;
        float*       ob = out + (size_t)b * D_ * S_;
        int s = q0 + ww * 32 + q;
        #pragma unroll
        for (int dt = 0; dt < 4; ++dt)
            #pragma unroll
            for (int r = 0; r < 16; ++r) {
                int dl = dt * 32 + (r & 3) + 8 * (r >> 2) + 4 * hi;
                float val = (o[dt][r] * c1 + obuf[dl * 32 + q] * c2) * inv;
                size_t g = (size_t)dl * S_ + s;
                ob[g] = xb[g] + val;
            }
    }
}

extern "C" void kernel_launch(void* const* d_in, const int* in_sizes, int n_in,
                              void* d_out, int out_size, void* d_ws, size_t ws_size,
                              hipStream_t stream) {
    const float* x  = (const float*)d_in[0];
    const float* Wq = (const float*)d_in[1];
    const float* bq = (const float*)d_in[2];
    const float* Wk = (const float*)d_in[3];
    const float* bk = (const float*)d_in[4];
    const float* Wv = (const float*)d_in[5];
    const float* bv = (const float*)d_in[6];
    float* out = (float*)d_out;

    size_t n = (size_t)B_ * S_ * D_;
    short* Qw = (short*)d_ws;
    short* Kw = Qw + n;
    short* Vw = Kw + n;
    short* Wf = (short*)d_out;   // scratch at head of d_out; fully overwritten

    wpack_kernel<<<24, 256, 0, stream>>>(Wq, Wk, Wv, Wf);

    dim3 grid(S_ / 64, B_);
    qkv_kernel<<<grid, 256, 0, stream>>>(x, Wf, bq, bk, bv, Qw, Kw, Vw);

    int smemB = 131072;
    (void)hipFuncSetAttribute((const void*)attn_kernel,
                              hipFuncAttributeMaxDynamicSharedMemorySize, smemB);
    attn_kernel<<<256, 512, smemB, stream>>>(Qw, Kw, Vw, x, out);
}